// Round 10
// baseline (322.520 us; speedup 1.0000x reference)
//
#include <hip/hip_runtime.h>
#include <hip/hip_fp16.h>
#include <math.h>

// DiagonalLSTM: B=8, Cin=HID=128, H=64, W=64, K=2, T = 2W-1 = 127 steps.
//
// Round 24 design (R23 overlap, contention-free grid):
//   - R23 post-mortem: 544-block fused grid co-scheduled zpre blocks onto
//     lstm CUs (2+ blocks/CU fit) -> lstm waves time-sliced against zpre
//     for most of the run (fused 258us). Sync machinery proven correct.
//   - Fix: grid = EXACTLY 256 blocks (32 lstm + 224 zpre) -> 1 block/CU,
//     zero co-residency. Each zpre block does 2-3 tiles (tt=j,j+224,j+448),
//     preserving r-major completion order (all r<28 done in iteration 1).
//     w_is frags loaded once per zpre block. lstm waves at s_setprio(1)
//     (zpre at 0) as insurance against residual co-scheduling.
//   - Sync: per-tile flags, producer __syncthreads (drains vmcnt) ->
//     agent release fence -> relaxed flag store; consumer one-time lazy
//     relaxed spin + acquire fence at first in-band zp prefetch (t=r-1).
//   - prep_k (launch 1): wp frags + zph bias slot + zflag=0 + hx fill.
//   - lstm loop byte-identical to proven R19: z via MFMA C-operand, two
//     independent 4-link MFMA chains, lazy mid-step hx boundary load,
//     LDS-only step barrier, 2x-unrolled t-loop, bias folded into zph,
//     incremental pointers, reg-buffered out stores, clamp-free fsig/ftanh.

#define HID 128
#define BB 8
#define HH 64
#define WW 64
#define TT 127

// prep items: 131072 wp | 512 bias | 512 zflag | 130048 hx-uint4
//           = 262144 = 1024 * 256 exactly
#define NPREP 1024

#define NZPRE 224  // zpre blocks; tiles tt = j, j+224, j+448(<512)

#define HROW 136  // padded LDS row stride in halfs

typedef _Float16 v8h __attribute__((ext_vector_type(8)));
typedef float v4f __attribute__((ext_vector_type(4)));

#define SENT64 0xFFFFFFFFFFFFFFFFULL  // 4x f16 -NaN (0xFF fill pattern)

__device__ __forceinline__ float fsig(float x) {
  float e = __builtin_amdgcn_exp2f(x * -1.44269504f);
  return __builtin_amdgcn_rcpf(1.f + e);
}
__device__ __forceinline__ float ftanh_(float x) {
  float e = __builtin_amdgcn_exp2f(x * 2.88539009f);
  return __builtin_fmaf(-2.f, __builtin_amdgcn_rcpf(1.f + e), 1.f);
}

// ---- prep kernel: wp frags + zph bias slot + zflag init + hx fill ----
__global__ __launch_bounds__(256) void prep_k(
    const float* __restrict__ w_ss, const float* __restrict__ b_is,
    const float* __restrict__ b_ss, _Float16* __restrict__ wp,
    __half* __restrict__ zph, unsigned* __restrict__ zflag,
    unsigned long long* __restrict__ hx) {
  int idx = blockIdx.x * 256 + threadIdx.x;
  if (idx < 131072) {
    // w_ss -> Wcat(512x256) A-frags: wp[(((mt*8+kt)*64+L)*8+j)]
    int j = idx & 7;
    int L = (idx >> 3) & 63;
    int kt = (idx >> 9) & 7;
    int mt = idx >> 12;
    int O = mt * 16 + (L & 15);
    int k = kt * 32 + ((L >> 4) & 3) * 8 + j;
    float v = (k < 128) ? w_ss[(size_t)O * 256 + k * 2]
                        : w_ss[(size_t)O * 256 + (k - 128) * 2 + 1];
    wp[idx] = (_Float16)v;
  } else if (idx < 131584) {
    // zph bias slot: layout idx2 = (u>>2)*16 + g*4 + (u&3)
    int idx2 = idx - 131072;  // 0..511
    int g = (idx2 >> 2) & 3;
    int u = (idx2 >> 4) * 4 + (idx2 & 3);
    int O = g * 128 + u;
    zph[(size_t)BB * HH * WW * 512 + idx2] = __float2half(b_is[O] + b_ss[O]);
  } else if (idx < 132096) {
    zflag[idx - 131584] = 0u;
  } else {
    // hx sentinel fill: 260096 u64 as 130048 x 16B
    int j = idx - 132096;
    uint4 s;
    s.x = 0xFFFFFFFFu; s.y = 0xFFFFFFFFu;
    s.z = 0xFFFFFFFFu; s.w = 0xFFFFFFFFu;
    ((uint4*)hx)[j] = s;
  }
}

// Step barrier: LDS-visibility only (no vmcnt drain; see R15 notes).
#define STEP_BARRIER()                                   \
  do {                                                   \
    asm volatile("s_waitcnt lgkmcnt(0)" ::: "memory");   \
    __builtin_amdgcn_s_barrier();                        \
    asm volatile("" ::: "memory");                       \
  } while (0)

#define HPLD(p) __hip_atomic_load((p), __ATOMIC_RELAXED, __HIP_MEMORY_SCOPE_AGENT)

// ---------------- R19 step body + one-time lazy zflag wait ----------------
#define STEP_BODY(T, RB)                                                       \
  do {                                                                         \
    /* phase 0: chain-0 LDS reads (slot rl) issued ASAP after barrier */       \
    v8h bfr[4];                                                                \
    _Pragma("unroll") for (int kt = 0; kt < 4; kt++)                           \
        bfr[kt] = *(const v8h*)&h_lds[RB][(rl * 2 + bl) * HROW + kt * 32 +     \
                                          quad * 8];                           \
    /* convert zu -> v4f (chain-1 C-operand init) */                           \
    v4f zi[4];                                                                 \
    _Pragma("unroll") for (int g = 0; g < 4; g++)                              \
        _Pragma("unroll") for (int i = 0; i < 4; i++)                          \
        zi[g][i] = __half2float(zu.h[g * 4 + i]);                              \
    /* zp prefetch for T+1; one-time flag wait at first in-band prefetch */    \
    {                                                                          \
      if (!zdone && (unsigned)wn < WW) {                                       \
        while (__hip_atomic_load(zf, __ATOMIC_RELAXED,                         \
                                 __HIP_MEMORY_SCOPE_AGENT) == 0u)              \
          __builtin_amdgcn_s_sleep(2);                                         \
        __builtin_amdgcn_fence(__ATOMIC_ACQUIRE, "agent");                     \
        zdone = true;                                                          \
      }                                                                        \
      const uint4* p = (const uint4*)(((unsigned)wn < WW) ? zcur : zbias);     \
      zu.q[0] = p[0];                                                          \
      zu.q[1] = p[1];                                                          \
      wn++;                                                                    \
      zcur += 512;                                                             \
    }                                                                          \
    /* MFMA: two independent 4-link chains; chain-1 accumulates onto z */      \
    v4f acc0[4], acc1[4];                                                      \
    _Pragma("unroll") for (int g = 0; g < 4; g++) {                            \
      acc0[g] = (v4f){0.f, 0.f, 0.f, 0.f};                                     \
      acc1[g] = zi[g];                                                         \
    }                                                                          \
    _Pragma("unroll") for (int kt = 0; kt < 4; kt++) {                         \
      _Pragma("unroll") for (int g = 0; g < 4; g++)                            \
          acc0[g] = __builtin_amdgcn_mfma_f32_16x16x32_f16(                    \
              wfrag[g][kt], bfr[kt], acc0[g], 0, 0, 0);                        \
    }                                                                          \
    _Pragma("unroll") for (int kt = 0; kt < 4; kt++) {                         \
      v8h bf1 = *(const v8h*)&h_lds[RB][((rl + 1) * 2 + bl) * HROW + kt * 32 + \
                                        quad * 8];                             \
      _Pragma("unroll") for (int g = 0; g < 4; g++)                            \
          acc1[g] = __builtin_amdgcn_mfma_f32_16x16x32_f16(                    \
              wfrag[g][4 + kt], bf1, acc1[g], 0, 0, 0);                        \
    }                                                                          \
    /* mid-step hx boundary load (R19 lazy): gates/pack/stores cover it */     \
    unsigned long long pend = 0ull;                                            \
    if (is_cons) pend = HPLD(ca);                                              \
    /* gates (bias pre-folded into zph -> rides in acc1) */                    \
    const int w = (T)-r;                                                       \
    const bool inband = ((unsigned)w < WW);                                    \
    float hv[4];                                                               \
    _Pragma("unroll") for (int rg2 = 0; rg2 < 4; rg2++) {                      \
      float z0 = acc0[0][rg2] + acc1[0][rg2];                                  \
      float z1 = acc0[1][rg2] + acc1[1][rg2];                                  \
      float z2 = acc0[2][rg2] + acc1[2][rg2];                                  \
      float z3 = acc0[3][rg2] + acc1[3][rg2];                                  \
      float iv = fsig(z0);                                                     \
      float fv = fsig(z1);                                                     \
      float ov = fsig(z2);                                                     \
      float gv = ftanh_(z3);                                                   \
      c[rg2] = fv * c[rg2] + iv * gv;                                          \
      hv[rg2] = ov * ftanh_(c[rg2]);                                           \
    }                                                                          \
    /* h(T) -> write-buffer slots 1..8 (LDS, 8B per lane) */                   \
    __half2 plo = __floats2half2_rn(hv[0], hv[1]);                             \
    __half2 phi = __floats2half2_rn(hv[2], hv[3]);                             \
    {                                                                          \
      uint2 pk;                                                                \
      pk.x = *(unsigned*)&plo;                                                 \
      pk.y = *(unsigned*)&phi;                                                 \
      *(uint2*)&h_lds[(RB) ^ 1][((rl + 1) * 2 + bl) * HROW + uq0] = pk;        \
    }                                                                          \
    /* export h(T)[R0+7]: fire-and-forget (data == flag, no drain) */          \
    if (rgr < 7 && l15 >= 14) {                                                \
      unsigned long long pk =                                                  \
          ((unsigned long long)*(unsigned*)&phi << 32) | *(unsigned*)&plo;     \
      __hip_atomic_store(pa_hx, pk, __ATOMIC_RELAXED,                          \
                         __HIP_MEMORY_SCOPE_AGENT);                            \
    }                                                                          \
    pa_hx += 2048;                                                             \
    /* out shift-window; coalesced 16B flush every 4 steps per cell */         \
    _Pragma("unroll") for (int rg2 = 0; rg2 < 4; rg2++) {                      \
      outb[rg2].x = outb[rg2].y;                                               \
      outb[rg2].y = outb[rg2].z;                                               \
      outb[rg2].z = outb[rg2].w;                                               \
      outb[rg2].w = hv[rg2];                                                   \
    }                                                                          \
    if (inband && (w & 3) == 3) {                                              \
      *(float4*)op0 = outb[0];                                                 \
      *(float4*)op1 = outb[1];                                                 \
      *(float4*)op2 = outb[2];                                                 \
      *(float4*)op3 = outb[3];                                                 \
      op0 += 4; op1 += 4; op2 += 4; op3 += 4;                                  \
    }                                                                          \
    /* validate pend (hx[T] = h(T)[R0-1]) -> wb slot 0 */                      \
    if (is_cons) {                                                             \
      while (__ballot(pend == SENT64) != 0ull) {                               \
        __builtin_amdgcn_s_sleep(1);                                           \
        pend = HPLD(ca);                                                       \
      }                                                                        \
      *(unsigned long long*)&h_lds[(RB) ^ 1][(0 * 2 + ebl) * HROW + eu] =      \
          pend;                                                                \
    }                                                                          \
    ca += 2048;                                                                \
    STEP_BARRIER();                                                            \
  } while (0)

// ---- fused kernel: blocks 0..31 lstm, blocks 32..255 zpre (2-3 tiles) ----
__global__ __launch_bounds__(512, 1) void fused(
    const __half* __restrict__ zph, const _Float16* __restrict__ wp,
    unsigned long long* __restrict__ hx, float* __restrict__ out,
    const float* __restrict__ x, const float* __restrict__ w_is,
    const float* __restrict__ b_is, const float* __restrict__ b_ss,
    unsigned* __restrict__ zflag, __half* __restrict__ zphw) {
  __shared__ _Float16 h_lds[2][9 * 2 * HROW];
  __shared__ _Float16 xt[64][136];

  const int blk = blockIdx.x;
  const int tid = threadIdx.x;
  const int L = tid & 63;
  const int quad = L >> 4;
  const int l15 = L & 15;

  if (blk >= 32) {
    // ================= zpre block: tiles j, j+224, j+448 =================
    const int j = blk - 32;    // 0..223
    const int wv8 = tid >> 6;  // 0..7; wave owns mt = 4*wv8 + m

    // w_is A-frags + bias, loaded ONCE (tile-independent):
    // lane L of tile (mt,kt) holds w_is[(mt*16+l15)*128 + kt*32 + quad*8 + jj]
    v8h wfr[4][4];
    float4 bvv[4];
#pragma unroll
    for (int m = 0; m < 4; m++) {
      const int mt = 4 * wv8 + m;
      const int O = mt * 16 + l15;
#pragma unroll
      for (int kt = 0; kt < 4; kt++) {
        const float* p = w_is + (size_t)O * 128 + kt * 32 + quad * 8;
        float4 a = *(const float4*)p;
        float4 b2 = *(const float4*)(p + 4);
        v8h f;
        f[0] = (_Float16)a.x;  f[1] = (_Float16)a.y;
        f[2] = (_Float16)a.z;  f[3] = (_Float16)a.w;
        f[4] = (_Float16)b2.x; f[5] = (_Float16)b2.y;
        f[6] = (_Float16)b2.z; f[7] = (_Float16)b2.w;
        wfr[m][kt] = f;
      }
      const int O4 = mt * 16 + quad * 4;
      float4 bi = *(const float4*)&b_is[O4];
      float4 bs4 = *(const float4*)&b_ss[O4];
      bvv[m] = make_float4(bi.x + bs4.x, bi.y + bs4.y, bi.z + bs4.z,
                           bi.w + bs4.w);
    }

    for (int tt = j; tt < 512; tt += NZPRE) {
      const int r = tt >> 3;  // r-major: iteration 1 covers all r<28
      const int b = tt & 7;

      __syncthreads();  // xt free (prev tile consumed)
      // stage x(b,:,r,:) -> xt transposed [w][c], 512-thread coalesced
      {
        const int cw = tid >> 4;        // 0..31
        const int w4 = (tid & 15) * 4;  // w base
#pragma unroll
        for (int p = 0; p < 4; p++) {
          int cc = p * 32 + cw;
          float4 v =
              *(const float4*)&x[(((size_t)b * 128 + cc) * HH + r) * WW + w4];
          xt[w4 + 0][cc] = (_Float16)v.x;
          xt[w4 + 1][cc] = (_Float16)v.y;
          xt[w4 + 2][cc] = (_Float16)v.z;
          xt[w4 + 3][cc] = (_Float16)v.w;
        }
      }
      __syncthreads();

#pragma unroll
      for (int nt = 0; nt < 4; nt++) {
        v8h bf[4];
#pragma unroll
        for (int kt = 0; kt < 4; kt++)
          bf[kt] = *(const v8h*)&xt[nt * 16 + l15][kt * 32 + quad * 8];
        const size_t pos = ((size_t)b * HH + r) * WW + nt * 16 + l15;
#pragma unroll
        for (int m = 0; m < 4; m++) {
          v4f acc = (v4f){0.f, 0.f, 0.f, 0.f};
#pragma unroll
          for (int kt = 0; kt < 4; kt++)
            acc = __builtin_amdgcn_mfma_f32_16x16x32_f16(wfr[m][kt], bf[kt],
                                                         acc, 0, 0, 0);
          const int mt = 4 * wv8 + m;
          __half2 lo = __floats2half2_rn(acc[0] + bvv[m].x, acc[1] + bvv[m].y);
          __half2 hi = __floats2half2_rn(acc[2] + bvv[m].z, acc[3] + bvv[m].w);
          uint2 pk;
          pk.x = *(unsigned*)&lo;
          pk.y = *(unsigned*)&hi;
          *(uint2*)&zphw[pos * 512 + ((mt & 7) * 4 + quad) * 16 +
                         (mt >> 3) * 4] = pk;
        }
      }

      // publish: __syncthreads drains every wave's stores (vmcnt 0),
      // release-fence, then coherent flag store.
      __syncthreads();
      if (tid == 0) {
        __builtin_amdgcn_fence(__ATOMIC_RELEASE, "agent");
        __hip_atomic_store(&zflag[tt], 1u, __ATOMIC_RELAXED,
                           __HIP_MEMORY_SCOPE_AGENT);
      }
    }
    return;
  }

  // ================= lstm block (R19, byte-identical loop) =================
  __builtin_amdgcn_s_setprio(1);  // win CU arbitration vs any co-resident work

  const int rgr = blk >> 2;
  const int bg = blk & 3;
  const int R0 = rgr * 8;
  const int wv = tid >> 6;
  const int rl = l15 >> 1;
  const int bl = l15 & 1;
  const int b = bg * 2 + bl;
  const int r = R0 + rl;
  const int uq0 = 16 * wv + quad * 4;
  const int zoff = (4 * wv + quad) * 16;

  for (int i = tid; i < (2 * 9 * 2 * HROW) / 2; i += 512)
    ((unsigned*)h_lds)[i] = 0u;

  // ---- weights as A-fragments, loaded once ----
  v8h wfrag[4][8];
  {
    const v8h* wp8 = (const v8h*)wp;
#pragma unroll
    for (int g = 0; g < 4; g++)
#pragma unroll
      for (int kt = 0; kt < 8; kt++)
        wfrag[g][kt] = wp8[((size_t)((8 * g + wv) * 8 + kt)) * 64 + L];
  }

  float c[4] = {0.f, 0.f, 0.f, 0.f};
  float4 outb[4];
#pragma unroll
  for (int i = 0; i < 4; i++) outb[i] = make_float4(0.f, 0.f, 0.f, 0.f);

  const int ebl = L >> 5;
  const int eu = (L & 31) * 4;
  const int exp_idx = bl * 32 + 4 * wv + quad;

  const bool is_cons = (wv == 0) && (rgr > 0);

  // ---- incremental pointers ----
  const __half* zpp = zph + ((size_t)b * HH + r) * WW * 512 + zoff;
  const __half* zbias = zph + (size_t)BB * HH * WW * 512 + zoff;
  const unsigned long long* ca =
      hx + (((size_t)(rgr > 0 ? rgr - 1 : 0) * 4 + bg) * 64 + L);
  unsigned long long* pa_hx = hx + (((size_t)rgr * 4 + bg) * 64 + exp_idx);
  float* op0 = out + (((size_t)b * HID + uq0 + 0) * HH + r) * WW;
  float* op1 = out + (((size_t)b * HID + uq0 + 1) * HH + r) * WW;
  float* op2 = out + (((size_t)b * HID + uq0 + 2) * HH + r) * WW;
  float* op3 = out + (((size_t)b * HID + uq0 + 3) * HH + r) * WW;

  // ---- zph readiness flag for this lane's (b,r) tile ----
  unsigned* zf = &zflag[r * 8 + b];
  bool zdone = false;

  // ---- zp for t=0 (w0 = -r: in-band only for r==0) ----
  union ZU {
    uint4 q[2];
    __half h[16];
  } zu;
  {
    if (r == 0) {  // r==0 lanes read real zph at t=0: wait for their tile
      while (__hip_atomic_load(zf, __ATOMIC_RELAXED,
                               __HIP_MEMORY_SCOPE_AGENT) == 0u)
        __builtin_amdgcn_s_sleep(2);
      __builtin_amdgcn_fence(__ATOMIC_ACQUIRE, "agent");
      zdone = true;
    }
    const uint4* p0 = (const uint4*)((r == 0) ? zpp : zbias);
    zu.q[0] = p0[0];
    zu.q[1] = p0[1];
  }
  int wn = 1 - r;
  const __half* zcur = zpp + (ptrdiff_t)wn * 512;

  __syncthreads();

  // 126 = 63x2 steps with static read-buffer index, then epilogue t=126.
  for (int t = 0; t < TT - 1; t += 2) {
    STEP_BODY(t, 0);
    STEP_BODY(t + 1, 1);
  }
  STEP_BODY(TT - 1, 0);
}

// ================= round-1 fallback path (proven correct) =================
__global__ __launch_bounds__(256) void transpose_x(const float* __restrict__ x,
                                                   float* __restrict__ xT) {
  int b = blockIdx.x >> 6;
  int r = blockIdx.x & 63;
  __shared__ float tile[32][65];
  for (int cc = 0; cc < 4; cc++) {
    int cl = threadIdx.x >> 6;
    int w = threadIdx.x & 63;
#pragma unroll
    for (int k = 0; k < 8; k++) {
      int c_loc = k * 4 + cl;
      int c = cc * 32 + c_loc;
      tile[c_loc][w] = x[(((size_t)b * 128 + c) * HH + r) * WW + w];
    }
    __syncthreads();
    int cs = threadIdx.x & 31;
    int wp = threadIdx.x >> 5;
#pragma unroll
    for (int k = 0; k < 8; k++) {
      int w2 = wp * 8 + k;
      xT[(((size_t)b * HH + r) * WW + w2) * 128 + cc * 32 + cs] = tile[cs][w2];
    }
    __syncthreads();
  }
}

__global__ __launch_bounds__(256) void step_kernel(
    const float* __restrict__ x, const float* __restrict__ xT, int use_xT,
    const float* __restrict__ w_is, const float* __restrict__ b_is,
    const float* __restrict__ w_ss, const float* __restrict__ b_ss,
    const float* __restrict__ h_prev, float* __restrict__ h_next,
    float* __restrict__ c_state, float* __restrict__ out, int t) {
  const int rg = blockIdx.x;
  const int q = blockIdx.y;
  const int r0 = rg * 2;
  const int tid = threadIdx.x;
  const int o_loc = tid & 63;
  const int k4 = tid >> 6;
  const int g_ = o_loc >> 4;
  const int u_ = o_loc & 15;
  const int O = g_ * 128 + q * 16 + u_;
  const int i0 = k4 * 32;

  __shared__ __align__(16) float h_in[3][BB][HID];
  __shared__ float zred[16][4][65];

  for (int idx = tid; idx < 3 * BB * HID; idx += 256) {
    int row_sel = idx >> 10;
    int rem = idx & 1023;
    int b = rem >> 7;
    int u = rem & 127;
    int rr = r0 - 1 + row_sel;
    h_in[row_sel][b][u] = (rr >= 0) ? h_prev[((size_t)b * HH + rr) * HID + u] : 0.0f;
  }

  float wr0[32], wr1[32], wz[32];
  {
    const float4* wss4 = (const float4*)(w_ss + ((size_t)O * 128 + i0) * 2);
#pragma unroll
    for (int j = 0; j < 16; j++) {
      float4 v = wss4[j];
      wr0[2 * j] = v.x;
      wr1[2 * j] = v.y;
      wr0[2 * j + 1] = v.z;
      wr1[2 * j + 1] = v.w;
    }
    const float4* wis4 = (const float4*)(w_is + (size_t)O * 128 + i0);
#pragma unroll
    for (int j = 0; j < 8; j++) {
      float4 v = wis4[j];
      wz[4 * j] = v.x;
      wz[4 * j + 1] = v.y;
      wz[4 * j + 2] = v.z;
      wz[4 * j + 3] = v.w;
    }
  }

  __syncthreads();

  float acc[2][BB];
#pragma unroll
  for (int rl = 0; rl < 2; rl++)
#pragma unroll
    for (int b = 0; b < BB; b++) acc[rl][b] = 0.0f;

#pragma unroll
  for (int jb = 0; jb < 8; jb++) {
    int ib = i0 + jb * 4;
#pragma unroll
    for (int b = 0; b < BB; b++) {
      const float4 hm4 = *(const float4*)&h_in[0][b][ib];
      const float4 hc4 = *(const float4*)&h_in[1][b][ib];
      const float4 hp4 = *(const float4*)&h_in[2][b][ib];
      const float* hm = (const float*)&hm4;
      const float* hc = (const float*)&hc4;
      const float* hq = (const float*)&hp4;
#pragma unroll
      for (int jj = 0; jj < 4; jj++) {
        float w0v = wr0[jb * 4 + jj];
        float w1v = wr1[jb * 4 + jj];
        acc[0][b] += w0v * hm[jj] + w1v * hc[jj];
        acc[1][b] += w0v * hc[jj] + w1v * hq[jj];
      }
    }
  }

#pragma unroll
  for (int rl = 0; rl < 2; rl++) {
    int rr = r0 + rl;
    int wcol = t - rr;
    if (wcol >= 0 && wcol < WW) {
      if (use_xT) {
        for (int b = 0; b < BB; b++) {
          const float4* xp =
              (const float4*)(xT + (((size_t)b * HH + rr) * WW + wcol) * 128 + i0);
#pragma unroll
          for (int j = 0; j < 8; j++) {
            float4 v = xp[j];
            acc[rl][b] += wz[4 * j] * v.x + wz[4 * j + 1] * v.y +
                          wz[4 * j + 2] * v.z + wz[4 * j + 3] * v.w;
          }
        }
      } else {
        for (int b = 0; b < BB; b++) {
          const float* xb = x + (((size_t)b * 128 + i0) * HH + rr) * WW + wcol;
#pragma unroll
          for (int j = 0; j < 32; j++) {
            acc[rl][b] += wz[j] * xb[(size_t)j * HH * WW];
          }
        }
      }
    }
  }

#pragma unroll
  for (int rl = 0; rl < 2; rl++)
#pragma unroll
    for (int b = 0; b < BB; b++) zred[rl * 8 + b][k4][o_loc] = acc[rl][b];
  __syncthreads();

  {
    int u = tid >> 4;
    int cell = tid & 15;
    int rl = cell >> 3;
    int b = cell & 7;
    int rr = r0 + rl;
    float z[4];
#pragma unroll
    for (int gg = 0; gg < 4; gg++) {
      int ol = gg * 16 + u;
      float s = zred[cell][0][ol] + zred[cell][1][ol] + zred[cell][2][ol] +
                zred[cell][3][ol];
      int Og = gg * 128 + q * 16 + u;
      z[gg] = s + b_is[Og] + b_ss[Og];
    }
    float iv = 1.0f / (1.0f + expf(-z[0]));
    float fv = 1.0f / (1.0f + expf(-z[1]));
    float ov = 1.0f / (1.0f + expf(-z[2]));
    float gv = tanhf(z[3]);
    int U = q * 16 + u;
    size_t sidx = ((size_t)b * HH + rr) * HID + U;
    float cv = c_state[sidx];
    float cn = fv * cv + iv * gv;
    c_state[sidx] = cn;
    float hn = ov * tanhf(cn);
    h_next[sidx] = hn;
    int wcol = t - rr;
    if (wcol >= 0 && wcol < WW) {
      out[(((size_t)b * HID + U) * HH + rr) * WW + wcol] = hn;
    }
  }
}

extern "C" void kernel_launch(void* const* d_in, const int* in_sizes, int n_in,
                              void* d_out, int out_size, void* d_ws,
                              size_t ws_size, hipStream_t stream) {
  const float* x = (const float*)d_in[0];
  const float* w_is = (const float*)d_in[1];
  const float* b_is = (const float*)d_in[2];
  const float* w_ss = (const float*)d_in[3];
  const float* b_ss = (const float*)d_in[4];
  float* outp = (float*)d_out;

  // zph has one extra 512-half bias slot at pos = B*H*W
  const size_t zph_bytes = ((size_t)BB * HH * WW * 512 + 512) * 2;
  const size_t wp_bytes = (size_t)512 * 256 * 2;  // 256 KiB
  const size_t hx_bytes = (size_t)TT * 8 * 4 * 64 * 8;
  const size_t zflag_bytes = 512 * sizeof(unsigned);
  const size_t need = zph_bytes + wp_bytes + hx_bytes + zflag_bytes;

  char* ws = (char*)d_ws;
  if (ws_size >= need) {
    __half* zph = (__half*)ws;
    _Float16* wpp = (_Float16*)(ws + zph_bytes);
    unsigned long long* hx =
        (unsigned long long*)(ws + zph_bytes + wp_bytes);
    unsigned* zflag = (unsigned*)(ws + zph_bytes + wp_bytes + hx_bytes);

    // launch 1: wp frags + zph bias slot + zflag=0 + hx sentinel fill
    prep_k<<<dim3(NPREP), 256, 0, stream>>>(w_ss, b_is, b_ss, wpp, zph,
                                            zflag, hx);
    // launch 2: fused lstm (0..31) + zpre (32..255, 2-3 tiles each);
    // 256 blocks total -> 1 block/CU, no co-residency with lstm.
    fused<<<dim3(32 + NZPRE), 512, 0, stream>>>(zph, wpp, hx, outp, x, w_is,
                                                b_is, b_ss, zflag, zph);
  } else {
    // -------- round-1 fallback --------
    const size_t xT_elems = (size_t)BB * HH * WW * 128;
    const size_t st_elems = (size_t)BB * HH * HID;
    const size_t need_xT = (xT_elems + 3 * st_elems) * sizeof(float);
    float* wsf = (float*)d_ws;
    float* xT = nullptr;
    float* st;
    int use_xT = 0;
    if (ws_size >= need_xT) {
      use_xT = 1;
      xT = wsf;
      st = wsf + xT_elems;
    } else {
      st = wsf;
    }
    float* h0 = st;
    float* h1 = st + st_elems;
    float* cb = st + 2 * st_elems;
    hipMemsetAsync(st, 0, 3 * st_elems * sizeof(float), stream);
    if (use_xT) transpose_x<<<dim3(BB * HH), 256, 0, stream>>>(x, xT);
    for (int t = 0; t < TT; t++) {
      float* hp = (t & 1) ? h1 : h0;
      float* hn = (t & 1) ? h0 : h1;
      step_kernel<<<dim3(32, 8), 256, 0, stream>>>(x, xT, use_xT, w_is, b_is,
                                                   w_ss, b_ss, hp, hn, cb, outp,
                                                   t);
    }
  }
}